// Round 2
// baseline (227.105 us; speedup 1.0000x reference)
//
#include <hip/hip_runtime.h>
#include <stdint.h>

#define BB    2048
#define DIN   4096
#define DOUT  4096
#define NW    64      // 64-bit words per DIN bits

// ---------------------------------------------------------------------------
// ws layout:
//   xp  : [NW][BB]   u64   offset 0        (1 MB)   bits of x rows
//   mp  : [NW][DOUT] u64   offset 1 MB     (2 MB)   bits of mask columns
//   flag: int              offset 3 MB              1 = masks are u8, 0 = int32
//
// Output is int32 0/1 (harness materializes the bool reference as int32 —
// round-1 absmax 1065353215 == float 1.0f bits minus 1 proved the boolean
// pattern itself was already exact).
// ---------------------------------------------------------------------------

// Detect whether the bool masks arrived as 1-byte (raw numpy bool) or as
// int32. Sum of the first 16384 bytes: u8-bool ~8192 ones; int32-LE ~2048
// (3/4 of bytes are zero padding). Data-dependent but identical every call.
__global__ void detect_mask_dtype(const unsigned char* __restrict__ m,
                                  int* __restrict__ flag) {
    __shared__ int s[256];
    int tid = threadIdx.x;
    int acc = 0;
    for (int i = tid; i < 16384; i += 256) acc += m[i];
    s[tid] = acc;
    __syncthreads();
    for (int stride = 128; stride > 0; stride >>= 1) {
        if (tid < stride) s[tid] += s[tid + stride];
        __syncthreads();
    }
    if (tid == 0) *flag = (s[0] > 5000) ? 1 : 0;
}

// Pack x (2048 x 4096 int32 of {0,1}) into xp[w][b]. One block per row;
// each wave ballots 64 coalesced elements into one u64 word.
__global__ void pack_x(const int* __restrict__ x,
                       unsigned long long* __restrict__ xp) {
    const int b    = blockIdx.x;
    const int tid  = threadIdx.x;
    const int wv   = tid >> 6;     // wave in block, 0..3
    const int lane = tid & 63;
    const int* row = x + (size_t)b * DIN;
    #pragma unroll
    for (int j = 0; j < 16; ++j) {
        int v = row[j * 256 + tid];
        unsigned long long word = __ballot(v != 0);
        if (lane == 0) xp[(size_t)(j * 4 + wv) * BB + b] = word;
    }
}

// Pack mask columns into mp[w][o]. Block = (w, o-tile of 1024); each thread
// builds 4 adjacent columns' words from 64 coalesced row reads.
__global__ void pack_m(const void* __restrict__ mraw,
                       unsigned long long* __restrict__ mp,
                       const int* __restrict__ flag) {
    const int w   = blockIdx.x;              // 0..63
    const int o0  = blockIdx.y * 1024;
    const int tid = threadIdx.x;
    const int o   = o0 + tid * 4;
    unsigned long long w0 = 0, w1 = 0, w2 = 0, w3 = 0;
    const int isU8 = *flag;
    if (isU8) {
        const uchar4* m8 = (const uchar4*)mraw;
        #pragma unroll 4
        for (int k = 0; k < 64; ++k) {
            uchar4 v = m8[(size_t)(w * 64 + k) * (DOUT / 4) + (o >> 2)];
            unsigned long long bit = 1ull << k;
            if (v.x) w0 |= bit;
            if (v.y) w1 |= bit;
            if (v.z) w2 |= bit;
            if (v.w) w3 |= bit;
        }
    } else {
        const int4* m32 = (const int4*)mraw;
        #pragma unroll 4
        for (int k = 0; k < 64; ++k) {
            int4 v = m32[(size_t)(w * 64 + k) * (DOUT / 4) + (o >> 2)];
            unsigned long long bit = 1ull << k;
            if (v.x) w0 |= bit;
            if (v.y) w1 |= bit;
            if (v.z) w2 |= bit;
            if (v.w) w3 |= bit;
        }
    }
    unsigned long long* dst = mp + (size_t)w * DOUT + o;
    dst[0] = w0; dst[1] = w1; dst[2] = w2; dst[3] = w3;
}

// Bit-GEMM: 128x128 tile per block, 256 threads, 8x8 register tile each.
// Ownership interleaved at stride 32 so LDS reads are contiguous 16B per
// lane-group (<=2-way bank aliasing, free). K staged in 16-word chunks.
__global__ __launch_bounds__(256, 2)
void bgemm(const unsigned long long* __restrict__ xp,
           const unsigned long long* __restrict__ mp,
           const int* __restrict__ thr,
           int* __restrict__ out) {
    const int o0  = blockIdx.x * 128;
    const int b0  = blockIdx.y * 128;
    const int tid = threadIdx.x;
    const int tx  = tid & 15;   // o dimension
    const int ty  = tid >> 4;   // b dimension

    __shared__ unsigned long long ldsx[16 * 128];
    __shared__ unsigned long long ldsm[16 * 128];

    unsigned int acc[8][8];
    #pragma unroll
    for (int i = 0; i < 8; ++i)
        #pragma unroll
        for (int j = 0; j < 8; ++j) acc[i][j] = 0;

    for (int chunk = 0; chunk < 4; ++chunk) {
        const int wbase = chunk * 16;
        // stage 16 w-rows of both operands (2048 u64 each) as 16B copies
        #pragma unroll
        for (int q = 0; q < 4; ++q) {
            int p  = q * 256 + tid;      // u64-pair index, 0..1023
            int w  = p >> 6;             // 0..15
            int b2 = (p & 63) * 2;       // 0..126 even
            ulonglong2 vx = *(const ulonglong2*)(xp + (size_t)(wbase + w) * BB + b0 + b2);
            *(ulonglong2*)(ldsx + w * 128 + b2) = vx;
            ulonglong2 vm = *(const ulonglong2*)(mp + (size_t)(wbase + w) * DOUT + o0 + b2);
            *(ulonglong2*)(ldsm + w * 128 + b2) = vm;
        }
        __syncthreads();

        #pragma unroll 2
        for (int w = 0; w < 16; ++w) {
            unsigned long long xv[8], mv[8];
            #pragma unroll
            for (int r = 0; r < 4; ++r) {
                ulonglong2 t = *(const ulonglong2*)(ldsx + w * 128 + ty * 2 + r * 32);
                xv[2 * r]     = t.x;
                xv[2 * r + 1] = t.y;
                ulonglong2 u = *(const ulonglong2*)(ldsm + w * 128 + tx * 2 + r * 32);
                mv[2 * r]     = u.x;
                mv[2 * r + 1] = u.y;
            }
            #pragma unroll
            for (int i = 0; i < 8; ++i)
                #pragma unroll
                for (int j = 0; j < 8; ++j)
                    acc[i][j] += __builtin_popcountll(xv[i] ^ mv[j]);
        }
        __syncthreads();
    }

    // epilogue: sums = 4096 - X; out = (sums > thr) = (X < 4096 - thr)
    // write int32 0/1 (reference bool -> int32 in the harness)
    int limj[8];
    #pragma unroll
    for (int j = 0; j < 8; ++j)
        limj[j] = DIN - thr[o0 + tx * 2 + (j >> 1) * 32 + (j & 1)];

    #pragma unroll
    for (int i = 0; i < 8; ++i) {
        int b = b0 + ty * 2 + (i >> 1) * 32 + (i & 1);
        int* orow = out + (size_t)b * DOUT + o0;
        #pragma unroll
        for (int j2 = 0; j2 < 4; ++j2) {
            int2 v;
            v.x = ((int)acc[i][2 * j2]     < limj[2 * j2])     ? 1 : 0;
            v.y = ((int)acc[i][2 * j2 + 1] < limj[2 * j2 + 1]) ? 1 : 0;
            *(int2*)(orow + tx * 2 + j2 * 32) = v;
        }
    }
}

extern "C" void kernel_launch(void* const* d_in, const int* in_sizes, int n_in,
                              void* d_out, int out_size, void* d_ws, size_t ws_size,
                              hipStream_t stream) {
    const int* x                   = (const int*)d_in[0];
    const void* masks              = d_in[1];           // bool: u8 or int32 (detected)
    const int* thresholds          = (const int*)d_in[2];
    int* out                       = (int*)d_out;

    unsigned long long* xp = (unsigned long long*)d_ws;                          // 1 MB
    unsigned long long* mp = (unsigned long long*)((char*)d_ws + (1 << 20));     // 2 MB
    int* flag              = (int*)((char*)d_ws + 3 * (1 << 20));

    detect_mask_dtype<<<1, 256, 0, stream>>>((const unsigned char*)masks, flag);
    pack_x<<<BB, 256, 0, stream>>>(x, xp);
    pack_m<<<dim3(NW, 4), 256, 0, stream>>>(masks, mp, flag);
    bgemm<<<dim3(DOUT / 128, BB / 128), 256, 0, stream>>>(xp, mp, thresholds, out);
}